// Round 14
// baseline (280.324 us; speedup 1.0000x reference)
//
#include <hip/hip_runtime.h>

#define N_NODES 50000
#define N_EDGES 800000
#define D 128
#define N_LAYERS 3
#define OUT_F 16
#define N_GRAPHS 128
#define NBUCK 391            // ceil(50000/128) buckets of 128 nodes
#define EPB 4096             // edges per partition block
#define NB3 ((N_EDGES + EPB - 1) / EPB)  // 196
#define CAP 4096             // padded bucket capacity (mean 2048, sigma ~45)
#define NT64 ((N_NODES + 63) / 64)       // 782 row-tiles of 64
#define PITCH 132            // LDS tile pitch in shorts (264B)
#define NCAST 6250           // cast blocks: 50000*128/4/256
#define NPREPW 96            // prep_w blocks: 24576/256

typedef __attribute__((ext_vector_type(8))) short short8;
typedef __attribute__((ext_vector_type(16))) float floatx16;

__device__ __forceinline__ unsigned short f2bf(float f) {
  unsigned int u = __float_as_uint(f);
  u += 0x7fff + ((u >> 16) & 1);   // RNE
  return (unsigned short)(u >> 16);
}
__device__ __forceinline__ float bf2f(unsigned short b) {
  return __uint_as_float(((unsigned int)b) << 16);
}
__device__ __forceinline__ float blo(unsigned v) { return __uint_as_float(v << 16); }
__device__ __forceinline__ float bhi(unsigned v) { return __uint_as_float(v & 0xffff0000u); }

// ====== prep_part: partition + cast x + weight frags in ONE dispatch ========
// (cursor zeroed by hipMemsetAsync before this dispatch)
__global__ __launch_bounds__(256) void prep_part_kernel(
    const int* __restrict__ src, const int* __restrict__ dst,
    int* __restrict__ cursor, unsigned* __restrict__ pairs,
    const float* __restrict__ x, unsigned short* __restrict__ x16,
    const float* __restrict__ Wrel, const float* __restrict__ Wroot,
    unsigned short* __restrict__ wt) {
  __shared__ unsigned pk[EPB];
  __shared__ int hist[NBUCK];
  __shared__ int wcur[NBUCK];
  const int bid = blockIdx.x;
  const int t = threadIdx.x;
  if (bid < NB3) {                         // ---- edge partition ----
    const int e0 = bid * EPB;
    const int n = min(EPB, N_EDGES - e0);
    for (int i = t; i < NBUCK; i += 256) hist[i] = 0;
    __syncthreads();
    for (int i = t; i < n; i += 256) {
      int d = dst[e0 + i], s = src[e0 + i];
      pk[i] = ((unsigned)d << 16) | (unsigned)s;
      atomicAdd(&hist[d >> 7], 1);
    }
    __syncthreads();
    for (int i = t; i < NBUCK; i += 256)
      wcur[i] = i * CAP + (hist[i] ? atomicAdd(&cursor[i], hist[i]) : 0);
    __syncthreads();
    for (int i = t; i < n; i += 256) {
      unsigned p = pk[i];
      int pos = atomicAdd(&wcur[p >> 23], 1);
      pairs[pos] = p;
    }
  } else if (bid < NB3 + NCAST) {          // ---- cast x (4 floats/thread) ----
    const int i = (bid - NB3) * 256 + t;
    const float4 v = *(const float4*)&x[(size_t)i * 4];
    uint2 o;
    o.x = f2bf(v.x) | ((unsigned)f2bf(v.y) << 16);
    o.y = f2bf(v.z) | ((unsigned)f2bf(v.w) << 16);
    *(uint2*)&x16[(size_t)i * 4] = o;
  } else {                                 // ---- weight fragments ----
    const int idx = (bid - NB3 - NCAST) * 256 + t;
    const int lane = idx & 63;
    const int kst = (idx >> 6) & 31;
    const int nt = (idx >> 11) & 1;
    const int half = (idx >> 12) & 1;
    const int l = idx >> 13;
    const int n = half * 64 + nt * 32 + (lane & 31);
    const int kx0 = kst * 16 + (lane >> 5) * 8;
    const int seg = kx0 >> 7;              // same seg for all 8 j
    const int k0 = kx0 & 127;
    const int mat = seg >> 1, lo = seg & 1;
    const float* W = (mat ? Wroot : Wrel) + (size_t)l * D * D;
    unsigned short v[8];
#pragma unroll
    for (int j = 0; j < 8; ++j) {
      float w = W[(size_t)(k0 + j) * D + n];
      unsigned short hi = f2bf(w);
      v[j] = lo ? f2bf(w - bf2f(hi)) : hi;
    }
    unsigned short* dstp =
        wt + ((size_t)l * 128 + (half * 2 + nt) * 32 + kst) * 512 + lane * 8;
    *(uint4*)dstp = *(const uint4*)v;
  }
}

// ===== bucket sort + PER-ROW SRC SORT (single change vs r13) ================
// After the dst-counting scatter, each row's edge list is sorted ascending by
// src (one thread per row, insertion sort, avg 16 / max ~45 elems). The
// gather's per-group request stream then sweeps the h table monotonically ->
// sequentialized L2-fill streams instead of random 64-128B requests.
__global__ __launch_bounds__(256) void bucket_sort_kernel(
    const unsigned* __restrict__ pairs, const int* __restrict__ cursor,
    int* __restrict__ rowbeg, int* __restrict__ rowend, int* __restrict__ esrc) {
  __shared__ unsigned pk[CAP];
  __shared__ int sorted[CAP];
  __shared__ int hist[128], off[128], cur[128];
  const int bkt = blockIdx.x;
  const int t = threadIdx.x;
  const int beg = bkt * CAP;
  const int cnt = cursor[bkt];
  if (t < 128) hist[t] = 0;
  __syncthreads();
  for (int i = t; i < cnt; i += 256) {
    unsigned p = pairs[beg + i];
    pk[i] = p;
    atomicAdd(&hist[(p >> 16) & 127], 1);
  }
  __syncthreads();
  if (t < 128) off[t] = hist[t];
  __syncthreads();
  for (int o = 1; o < 128; o <<= 1) {
    int x = (t < 128 && t >= o) ? off[t - o] : 0;
    __syncthreads();
    if (t < 128) off[t] += x;
    __syncthreads();
  }
  if (t < 128) {
    int node = bkt * 128 + t;
    if (node < N_NODES) {
      rowbeg[node] = beg + off[t] - hist[t];
      rowend[node] = beg + off[t];
    }
    cur[t] = off[t] - hist[t];
  }
  __syncthreads();
  for (int i = t; i < cnt; i += 256) {
    unsigned p = pk[i];
    int pos = atomicAdd(&cur[(p >> 16) & 127], 1);
    sorted[pos] = (int)(p & 0xFFFFu);
  }
  __syncthreads();
  // ---- per-row src sort (ascending) ----
  if (t < 128) {
    const int rb = off[t] - hist[t], re = off[t];
    for (int i = rb + 1; i < re; ++i) {
      const int key = sorted[i];
      int j = i - 1;
      while (j >= rb && sorted[j] > key) { sorted[j + 1] = sorted[j]; --j; }
      sorted[j + 1] = key;
    }
  }
  __syncthreads();
  for (int i = t; i < cnt; i += 256) esrc[beg + i] = sorted[i];
}

// ========== FUSED layer v13 (unchanged): 64-row block, ONE barrier ==========
// 8-wave block = 2 tiles of 32 rows. Gather: 32 groups x 16 lanes, TWO rows
// per group, (512,8)/32-VGPR config (measured best). MFMA: wave w ->
// (tile w&1, phase w>>1); 32 ksteps both chains into one accumulator.
__global__ __launch_bounds__(512, 8) void layer_kernel(
    const unsigned short* __restrict__ h,     // [N][128] bf16 row-major
    const int* __restrict__ rowbeg, const int* __restrict__ rowend,
    const int* __restrict__ esrc,
    const unsigned short* __restrict__ wt,    // this layer's 128KB frag block
    const float* __restrict__ brel,
    unsigned short* __restrict__ outp) {      // [N][128] bf16 row-major
  __shared__ unsigned short atile[64 * PITCH];  // agg tiles  (16.9 KB)
  __shared__ unsigned short htile[64 * PITCH];  // root tiles (16.9 KB)
  const int t = threadIdx.x;
  const int r0 = blockIdx.x * 64;
  const int g = t >> 4, li = t & 15;            // 32 groups x 16 lanes
  const unsigned short* hp = h + (size_t)li * 8;

#pragma unroll
  for (int rr = 0; rr < 2; ++rr) {
    const int lr = g + rr * 32;
    const int row = r0 + lr;
    // ---- stage root row (coalesced; zero tail rows) ----
    if (row < N_NODES) {
      *(uint4*)&htile[lr * PITCH + li * 8] =
          *(const uint4*)&h[(size_t)row * D + li * 8];
    } else {
      const uint4 z = {0, 0, 0, 0};
      *(uint4*)&htile[lr * PITCH + li * 8] = z;
    }
    // ---- gather: 16 lanes read full 256B source row, 4-edge unroll ----
    int beg = 0, end = 0;
    if (row < N_NODES) { beg = rowbeg[row]; end = rowend[row]; }
    float a0 = 0, a1 = 0, a2 = 0, a3 = 0, a4 = 0, a5 = 0, a6 = 0, a7 = 0;
    int e = beg;
    for (; e + 4 <= end; e += 4) {
      const int s0 = esrc[e],     s1 = esrc[e + 1];
      const int s2 = esrc[e + 2], s3 = esrc[e + 3];
      const uint4 v0 = *(const uint4*)&hp[(size_t)s0 * D];
      const uint4 v1 = *(const uint4*)&hp[(size_t)s1 * D];
      const uint4 v2 = *(const uint4*)&hp[(size_t)s2 * D];
      const uint4 v3 = *(const uint4*)&hp[(size_t)s3 * D];
      a0 += blo(v0.x) + blo(v1.x) + blo(v2.x) + blo(v3.x);
      a1 += bhi(v0.x) + bhi(v1.x) + bhi(v2.x) + bhi(v3.x);
      a2 += blo(v0.y) + blo(v1.y) + blo(v2.y) + blo(v3.y);
      a3 += bhi(v0.y) + bhi(v1.y) + bhi(v2.y) + bhi(v3.y);
      a4 += blo(v0.z) + blo(v1.z) + blo(v2.z) + blo(v3.z);
      a5 += bhi(v0.z) + bhi(v1.z) + bhi(v2.z) + bhi(v3.z);
      a6 += blo(v0.w) + blo(v1.w) + blo(v2.w) + blo(v3.w);
      a7 += bhi(v0.w) + bhi(v1.w) + bhi(v2.w) + bhi(v3.w);
    }
    for (; e < end; ++e) {
      const uint4 v0 = *(const uint4*)&hp[(size_t)esrc[e] * D];
      a0 += blo(v0.x); a1 += bhi(v0.x);
      a2 += blo(v0.y); a3 += bhi(v0.y);
      a4 += blo(v0.z); a5 += bhi(v0.z);
      a6 += blo(v0.w); a7 += bhi(v0.w);
    }
    uint4 o;
    o.x = f2bf(a0) | ((unsigned)f2bf(a1) << 16);
    o.y = f2bf(a2) | ((unsigned)f2bf(a3) << 16);
    o.z = f2bf(a4) | ((unsigned)f2bf(a5) << 16);
    o.w = f2bf(a6) | ((unsigned)f2bf(a7) << 16);
    *(uint4*)&atile[lr * PITCH + li * 8] = o;
  }
  __syncthreads();   // the only barrier

  // ---- MFMA: wave w = (tile w&1, phase w>>1); 32 ksteps, both chains ----
  const int wave = t >> 6, lane = t & 63;
  const int tl = wave & 1, p = wave >> 1;
  const int r2 = lane & 31, hseg = lane >> 5;
  const int rbase = tl * 32 + r2;
  short8 ag[8], hh[8];
#pragma unroll
  for (int i = 0; i < 8; ++i) {
    ag[i] = *(const short8*)&atile[rbase * PITCH + i * 16 + hseg * 8];
    hh[i] = *(const short8*)&htile[rbase * PITCH + i * 16 + hseg * 8];
  }
  const unsigned short* ws = wt + (size_t)p * 32 * 512;
  floatx16 acc = {0.f};
#pragma unroll
  for (int kst = 0; kst < 32; ++kst) {
    const short8 af = (kst < 16) ? ag[kst & 7] : hh[kst & 7];
    const short8 b = *(const short8*)&ws[(size_t)kst * 512 + lane * 8];
    acc = __builtin_amdgcn_mfma_f32_32x32x16_bf16(af, b, acc, 0, 0, 0);
  }
  const int cb = p * 32 + r2;
  const float bias = brel[cb];
#pragma unroll
  for (int reg = 0; reg < 16; ++reg) {
    const int orow = r0 + tl * 32 + (reg & 3) + 8 * (reg >> 2) + 4 * hseg;
    if (orow < N_NODES)
      outp[(size_t)orow * D + cb] = f2bf(fmaxf(acc[reg] + bias, 0.f));
  }
}

// ============= pool (segment ranges; batch sorted) + MLP head ===============
__device__ __forceinline__ int lb_search(const int* __restrict__ a, int n, int key) {
  int lo = 0, hi = n;
  while (lo < hi) {
    int m = (lo + hi) >> 1;
    if (a[m] < key) lo = m + 1; else hi = m;
  }
  return lo;
}

__global__ __launch_bounds__(256) void pool_head_kernel(
    const unsigned short* __restrict__ h, const int* __restrict__ batch,
    const float* __restrict__ W1, const float* __restrict__ b1,
    const float* __restrict__ W2, const float* __restrict__ b2,
    float* __restrict__ out) {
  __shared__ float sums_lds[16][128];
  __shared__ float pooled[128];
  __shared__ float hidden[128];
  __shared__ int range[2];
  const int g = blockIdx.x;
  const int t = threadIdx.x;
  if (t < 2) range[t] = lb_search(batch, N_NODES, g + t);
  __syncthreads();
  const int lo = range[0], hi = range[1];
  const int rg = t >> 4, cg = t & 15;
  float a0 = 0, a1 = 0, a2 = 0, a3 = 0, a4 = 0, a5 = 0, a6 = 0, a7 = 0;
  for (int n = lo + rg; n < hi; n += 16) {
    const uint4 v = *(const uint4*)&h[(size_t)n * D + cg * 8];
    a0 += blo(v.x); a1 += bhi(v.x);
    a2 += blo(v.y); a3 += bhi(v.y);
    a4 += blo(v.z); a5 += bhi(v.z);
    a6 += blo(v.w); a7 += bhi(v.w);
  }
  sums_lds[rg][cg * 8 + 0] = a0; sums_lds[rg][cg * 8 + 1] = a1;
  sums_lds[rg][cg * 8 + 2] = a2; sums_lds[rg][cg * 8 + 3] = a3;
  sums_lds[rg][cg * 8 + 4] = a4; sums_lds[rg][cg * 8 + 5] = a5;
  sums_lds[rg][cg * 8 + 6] = a6; sums_lds[rg][cg * 8 + 7] = a7;
  __syncthreads();
  if (t < 128) {
    float s = 0.f;
#pragma unroll
    for (int r = 0; r < 16; ++r) s += sums_lds[r][t];
    pooled[t] = s / fmaxf((float)(hi - lo), 1.f);
  }
  __syncthreads();
  if (t < 128) {
    float a = b1[t];
    for (int k = 0; k < D; ++k) a += pooled[k] * W1[k * D + t];
    hidden[t] = a;
  }
  __syncthreads();
  if (t < OUT_F) {
    float o = b2[t];
    for (int k = 0; k < D; ++k) o += hidden[k] * W2[k * OUT_F + t];
    out[(size_t)g * OUT_F + t] = o;
  }
}

// ============================== launch ======================================
extern "C" void kernel_launch(void* const* d_in, const int* in_sizes, int n_in,
                              void* d_out, int out_size, void* d_ws, size_t ws_size,
                              hipStream_t stream) {
  const float* x     = (const float*)d_in[0];
  const int*   ei    = (const int*)d_in[1];
  const int*   batch = (const int*)d_in[2];
  const float* Wrel  = (const float*)d_in[3];
  const float* brel  = (const float*)d_in[4];
  const float* Wroot = (const float*)d_in[5];
  const float* W1    = (const float*)d_in[6];
  const float* b1    = (const float*)d_in[7];
  const float* W2    = (const float*)d_in[8];
  const float* b2    = (const float*)d_in[9];
  float* out = (float*)d_out;

  const size_t ND = (size_t)N_NODES * D;
  unsigned short* bufA = (unsigned short*)d_ws;            // N*D bf16
  unsigned short* bufB = bufA + ND;                        // N*D bf16
  unsigned short* bufC = bufB + ND;                        // N*D bf16 (x16)
  unsigned short* wt   = bufC + ND;                        // 3*128*512 bf16
  int* rowbeg = (int*)(wt + (size_t)N_LAYERS * 128 * 512); // N
  int* rowend = rowbeg + N_NODES;                          // N
  int* esrc   = rowend + N_NODES;                          // NBUCK*CAP
  unsigned* pairs = (unsigned*)(esrc + (size_t)NBUCK * CAP);  // NBUCK*CAP
  int* cursor = (int*)(pairs + (size_t)NBUCK * CAP);       // NBUCK

  const int* esrc_in = ei;
  const int* edst_in = ei + N_EDGES;

  // ---- prep (partition + cast + weight frags) then bucket sort ----
  hipMemsetAsync(cursor, 0, NBUCK * sizeof(int), stream);
  prep_part_kernel<<<NB3 + NCAST + NPREPW, 256, 0, stream>>>(
      esrc_in, edst_in, cursor, pairs, x, bufC, Wrel, Wroot, wt);
  bucket_sort_kernel<<<NBUCK, 256, 0, stream>>>(pairs, cursor, rowbeg, rowend, esrc);

  // ---- 3 fused layers (gather + GEMM in one kernel each) ----
  const size_t WL = (size_t)128 * 512;
  layer_kernel<<<NT64, 512, 0, stream>>>(bufC, rowbeg, rowend, esrc,
                                         wt, brel, bufA);
  layer_kernel<<<NT64, 512, 0, stream>>>(bufA, rowbeg, rowend, esrc,
                                         wt + WL, brel + D, bufB);
  layer_kernel<<<NT64, 512, 0, stream>>>(bufB, rowbeg, rowend, esrc,
                                         wt + 2 * WL, brel + 2 * D, bufA);

  pool_head_kernel<<<N_GRAPHS, 256, 0, stream>>>(bufA, batch, W1, b1, W2, b2, out);
}

// Round 15
// 255.787 us; speedup vs baseline: 1.0959x; 1.0959x over previous
//
#include <hip/hip_runtime.h>

#define N_NODES 50000
#define N_EDGES 800000
#define D 128
#define N_LAYERS 3
#define OUT_F 16
#define N_GRAPHS 128
#define NBUCK 391            // ceil(50000/128) buckets of 128 nodes
#define EPB 4096             // edges per partition block
#define NB3 ((N_EDGES + EPB - 1) / EPB)  // 196
#define CAP 4096             // padded bucket capacity (mean 2048, sigma ~45)
#define NT64 ((N_NODES + 63) / 64)       // 782 row-tiles of 64
#define PITCH 132            // LDS tile pitch in shorts (264B)
#define NCAST 6250           // cast blocks: 50000*128/4/256
#define NPREPW 96            // prep_w blocks: 24576/256

typedef __attribute__((ext_vector_type(8))) short short8;
typedef __attribute__((ext_vector_type(16))) float floatx16;

__device__ __forceinline__ unsigned short f2bf(float f) {
  unsigned int u = __float_as_uint(f);
  u += 0x7fff + ((u >> 16) & 1);   // RNE
  return (unsigned short)(u >> 16);
}
__device__ __forceinline__ float bf2f(unsigned short b) {
  return __uint_as_float(((unsigned int)b) << 16);
}
__device__ __forceinline__ float blo(unsigned v) { return __uint_as_float(v << 16); }
__device__ __forceinline__ float bhi(unsigned v) { return __uint_as_float(v & 0xffff0000u); }

// ====== prep_part: partition + cast x + weight frags in ONE dispatch ========
// (cursor zeroed by hipMemsetAsync before this dispatch)
__global__ __launch_bounds__(256) void prep_part_kernel(
    const int* __restrict__ src, const int* __restrict__ dst,
    int* __restrict__ cursor, unsigned* __restrict__ pairs,
    const float* __restrict__ x, unsigned short* __restrict__ x16,
    const float* __restrict__ Wrel, const float* __restrict__ Wroot,
    unsigned short* __restrict__ wt) {
  __shared__ unsigned pk[EPB];
  __shared__ int hist[NBUCK];
  __shared__ int wcur[NBUCK];
  const int bid = blockIdx.x;
  const int t = threadIdx.x;
  if (bid < NB3) {                         // ---- edge partition ----
    const int e0 = bid * EPB;
    const int n = min(EPB, N_EDGES - e0);
    for (int i = t; i < NBUCK; i += 256) hist[i] = 0;
    __syncthreads();
    for (int i = t; i < n; i += 256) {
      int d = dst[e0 + i], s = src[e0 + i];
      pk[i] = ((unsigned)d << 16) | (unsigned)s;
      atomicAdd(&hist[d >> 7], 1);
    }
    __syncthreads();
    for (int i = t; i < NBUCK; i += 256)
      wcur[i] = i * CAP + (hist[i] ? atomicAdd(&cursor[i], hist[i]) : 0);
    __syncthreads();
    for (int i = t; i < n; i += 256) {
      unsigned p = pk[i];
      int pos = atomicAdd(&wcur[p >> 23], 1);
      pairs[pos] = p;
    }
  } else if (bid < NB3 + NCAST) {          // ---- cast x (4 floats/thread) ----
    const int i = (bid - NB3) * 256 + t;
    const float4 v = *(const float4*)&x[(size_t)i * 4];
    uint2 o;
    o.x = f2bf(v.x) | ((unsigned)f2bf(v.y) << 16);
    o.y = f2bf(v.z) | ((unsigned)f2bf(v.w) << 16);
    *(uint2*)&x16[(size_t)i * 4] = o;
  } else {                                 // ---- weight fragments ----
    const int idx = (bid - NB3 - NCAST) * 256 + t;
    const int lane = idx & 63;
    const int kst = (idx >> 6) & 31;
    const int nt = (idx >> 11) & 1;
    const int half = (idx >> 12) & 1;
    const int l = idx >> 13;
    const int n = half * 64 + nt * 32 + (lane & 31);
    const int kx0 = kst * 16 + (lane >> 5) * 8;
    const int seg = kx0 >> 7;              // same seg for all 8 j
    const int k0 = kx0 & 127;
    const int mat = seg >> 1, lo = seg & 1;
    const float* W = (mat ? Wroot : Wrel) + (size_t)l * D * D;
    unsigned short v[8];
#pragma unroll
    for (int j = 0; j < 8; ++j) {
      float w = W[(size_t)(k0 + j) * D + n];
      unsigned short hi = f2bf(w);
      v[j] = lo ? f2bf(w - bf2f(hi)) : hi;
    }
    unsigned short* dstp =
        wt + ((size_t)l * 128 + (half * 2 + nt) * 32 + kst) * 512 + lane * 8;
    *(uint4*)dstp = *(const uint4*)v;
  }
}

// ===== bucket sort + PARALLEL per-row src sort (rank-based) =================
// r14 proved sorted rows help the gather (~4us/layer) but its serial
// insertion sort cost 50us. Replacement: every thread ranks elements
// i = t, t+256, ... — binary-search the row in off[], scan the row (avg 16)
// counting (v_j, j) < (v_i, i), write val to pk[rb+rank]. All 256 lanes
// busy, no serial chain, unique ranks (index tie-break), deterministic
// ascending output -> identical math to r14 (absmax-verified).
__global__ __launch_bounds__(256) void bucket_sort_kernel(
    const unsigned* __restrict__ pairs, const int* __restrict__ cursor,
    int* __restrict__ rowbeg, int* __restrict__ rowend, int* __restrict__ esrc) {
  __shared__ unsigned pk[CAP];
  __shared__ int sorted[CAP];
  __shared__ int hist[128], off[128], cur[128];
  const int bkt = blockIdx.x;
  const int t = threadIdx.x;
  const int beg = bkt * CAP;
  const int cnt = cursor[bkt];
  if (t < 128) hist[t] = 0;
  __syncthreads();
  for (int i = t; i < cnt; i += 256) {
    unsigned p = pairs[beg + i];
    pk[i] = p;
    atomicAdd(&hist[(p >> 16) & 127], 1);
  }
  __syncthreads();
  if (t < 128) off[t] = hist[t];
  __syncthreads();
  for (int o = 1; o < 128; o <<= 1) {
    int x = (t < 128 && t >= o) ? off[t - o] : 0;
    __syncthreads();
    if (t < 128) off[t] += x;
    __syncthreads();
  }
  if (t < 128) {
    int node = bkt * 128 + t;
    if (node < N_NODES) {
      rowbeg[node] = beg + off[t] - hist[t];
      rowend[node] = beg + off[t];
    }
    cur[t] = off[t] - hist[t];
  }
  __syncthreads();
  for (int i = t; i < cnt; i += 256) {
    unsigned p = pk[i];
    int pos = atomicAdd(&cur[(p >> 16) & 127], 1);
    sorted[pos] = (int)(p & 0xFFFFu);
  }
  __syncthreads();
  // ---- parallel rank sort within each row (ascending src) ----
  for (int i = t; i < cnt; i += 256) {
    const int val = sorted[i];
    int lo = 0, hi = 127;                  // find row: smallest r, off[r] > i
    while (lo < hi) { int m = (lo + hi) >> 1; if (off[m] > i) hi = m; else lo = m + 1; }
    const int rb = lo ? off[lo - 1] : 0;
    const int re = off[lo];
    int rank = 0;
    for (int j = rb; j < re; ++j) {
      const int vj = sorted[j];
      rank += (vj < val) || (vj == val && j < i);
    }
    pk[rb + rank] = (unsigned)val;
  }
  __syncthreads();
  for (int i = t; i < cnt; i += 256) esrc[beg + i] = (int)pk[i];
}

// ========== FUSED layer v13 (unchanged): 64-row block, ONE barrier ==========
// 8-wave block = 2 tiles of 32 rows. Gather: 32 groups x 16 lanes, TWO rows
// per group, (512,8)/32-VGPR config (measured best). MFMA: wave w ->
// (tile w&1, phase w>>1); 32 ksteps both chains into one accumulator.
__global__ __launch_bounds__(512, 8) void layer_kernel(
    const unsigned short* __restrict__ h,     // [N][128] bf16 row-major
    const int* __restrict__ rowbeg, const int* __restrict__ rowend,
    const int* __restrict__ esrc,
    const unsigned short* __restrict__ wt,    // this layer's 128KB frag block
    const float* __restrict__ brel,
    unsigned short* __restrict__ outp) {      // [N][128] bf16 row-major
  __shared__ unsigned short atile[64 * PITCH];  // agg tiles  (16.9 KB)
  __shared__ unsigned short htile[64 * PITCH];  // root tiles (16.9 KB)
  const int t = threadIdx.x;
  const int r0 = blockIdx.x * 64;
  const int g = t >> 4, li = t & 15;            // 32 groups x 16 lanes
  const unsigned short* hp = h + (size_t)li * 8;

#pragma unroll
  for (int rr = 0; rr < 2; ++rr) {
    const int lr = g + rr * 32;
    const int row = r0 + lr;
    // ---- stage root row (coalesced; zero tail rows) ----
    if (row < N_NODES) {
      *(uint4*)&htile[lr * PITCH + li * 8] =
          *(const uint4*)&h[(size_t)row * D + li * 8];
    } else {
      const uint4 z = {0, 0, 0, 0};
      *(uint4*)&htile[lr * PITCH + li * 8] = z;
    }
    // ---- gather: 16 lanes read full 256B source row, 4-edge unroll ----
    int beg = 0, end = 0;
    if (row < N_NODES) { beg = rowbeg[row]; end = rowend[row]; }
    float a0 = 0, a1 = 0, a2 = 0, a3 = 0, a4 = 0, a5 = 0, a6 = 0, a7 = 0;
    int e = beg;
    for (; e + 4 <= end; e += 4) {
      const int s0 = esrc[e],     s1 = esrc[e + 1];
      const int s2 = esrc[e + 2], s3 = esrc[e + 3];
      const uint4 v0 = *(const uint4*)&hp[(size_t)s0 * D];
      const uint4 v1 = *(const uint4*)&hp[(size_t)s1 * D];
      const uint4 v2 = *(const uint4*)&hp[(size_t)s2 * D];
      const uint4 v3 = *(const uint4*)&hp[(size_t)s3 * D];
      a0 += blo(v0.x) + blo(v1.x) + blo(v2.x) + blo(v3.x);
      a1 += bhi(v0.x) + bhi(v1.x) + bhi(v2.x) + bhi(v3.x);
      a2 += blo(v0.y) + blo(v1.y) + blo(v2.y) + blo(v3.y);
      a3 += bhi(v0.y) + bhi(v1.y) + bhi(v2.y) + bhi(v3.y);
      a4 += blo(v0.z) + blo(v1.z) + blo(v2.z) + blo(v3.z);
      a5 += bhi(v0.z) + bhi(v1.z) + bhi(v2.z) + bhi(v3.z);
      a6 += blo(v0.w) + blo(v1.w) + blo(v2.w) + blo(v3.w);
      a7 += bhi(v0.w) + bhi(v1.w) + bhi(v2.w) + bhi(v3.w);
    }
    for (; e < end; ++e) {
      const uint4 v0 = *(const uint4*)&hp[(size_t)esrc[e] * D];
      a0 += blo(v0.x); a1 += bhi(v0.x);
      a2 += blo(v0.y); a3 += bhi(v0.y);
      a4 += blo(v0.z); a5 += bhi(v0.z);
      a6 += blo(v0.w); a7 += bhi(v0.w);
    }
    uint4 o;
    o.x = f2bf(a0) | ((unsigned)f2bf(a1) << 16);
    o.y = f2bf(a2) | ((unsigned)f2bf(a3) << 16);
    o.z = f2bf(a4) | ((unsigned)f2bf(a5) << 16);
    o.w = f2bf(a6) | ((unsigned)f2bf(a7) << 16);
    *(uint4*)&atile[lr * PITCH + li * 8] = o;
  }
  __syncthreads();   // the only barrier

  // ---- MFMA: wave w = (tile w&1, phase w>>1); 32 ksteps, both chains ----
  const int wave = t >> 6, lane = t & 63;
  const int tl = wave & 1, p = wave >> 1;
  const int r2 = lane & 31, hseg = lane >> 5;
  const int rbase = tl * 32 + r2;
  short8 ag[8], hh[8];
#pragma unroll
  for (int i = 0; i < 8; ++i) {
    ag[i] = *(const short8*)&atile[rbase * PITCH + i * 16 + hseg * 8];
    hh[i] = *(const short8*)&htile[rbase * PITCH + i * 16 + hseg * 8];
  }
  const unsigned short* ws = wt + (size_t)p * 32 * 512;
  floatx16 acc = {0.f};
#pragma unroll
  for (int kst = 0; kst < 32; ++kst) {
    const short8 af = (kst < 16) ? ag[kst & 7] : hh[kst & 7];
    const short8 b = *(const short8*)&ws[(size_t)kst * 512 + lane * 8];
    acc = __builtin_amdgcn_mfma_f32_32x32x16_bf16(af, b, acc, 0, 0, 0);
  }
  const int cb = p * 32 + r2;
  const float bias = brel[cb];
#pragma unroll
  for (int reg = 0; reg < 16; ++reg) {
    const int orow = r0 + tl * 32 + (reg & 3) + 8 * (reg >> 2) + 4 * hseg;
    if (orow < N_NODES)
      outp[(size_t)orow * D + cb] = f2bf(fmaxf(acc[reg] + bias, 0.f));
  }
}

// ============= pool (segment ranges; batch sorted) + MLP head ===============
__device__ __forceinline__ int lb_search(const int* __restrict__ a, int n, int key) {
  int lo = 0, hi = n;
  while (lo < hi) {
    int m = (lo + hi) >> 1;
    if (a[m] < key) lo = m + 1; else hi = m;
  }
  return lo;
}

__global__ __launch_bounds__(256) void pool_head_kernel(
    const unsigned short* __restrict__ h, const int* __restrict__ batch,
    const float* __restrict__ W1, const float* __restrict__ b1,
    const float* __restrict__ W2, const float* __restrict__ b2,
    float* __restrict__ out) {
  __shared__ float sums_lds[16][128];
  __shared__ float pooled[128];
  __shared__ float hidden[128];
  __shared__ int range[2];
  const int g = blockIdx.x;
  const int t = threadIdx.x;
  if (t < 2) range[t] = lb_search(batch, N_NODES, g + t);
  __syncthreads();
  const int lo = range[0], hi = range[1];
  const int rg = t >> 4, cg = t & 15;
  float a0 = 0, a1 = 0, a2 = 0, a3 = 0, a4 = 0, a5 = 0, a6 = 0, a7 = 0;
  for (int n = lo + rg; n < hi; n += 16) {
    const uint4 v = *(const uint4*)&h[(size_t)n * D + cg * 8];
    a0 += blo(v.x); a1 += bhi(v.x);
    a2 += blo(v.y); a3 += bhi(v.y);
    a4 += blo(v.z); a5 += bhi(v.z);
    a6 += blo(v.w); a7 += bhi(v.w);
  }
  sums_lds[rg][cg * 8 + 0] = a0; sums_lds[rg][cg * 8 + 1] = a1;
  sums_lds[rg][cg * 8 + 2] = a2; sums_lds[rg][cg * 8 + 3] = a3;
  sums_lds[rg][cg * 8 + 4] = a4; sums_lds[rg][cg * 8 + 5] = a5;
  sums_lds[rg][cg * 8 + 6] = a6; sums_lds[rg][cg * 8 + 7] = a7;
  __syncthreads();
  if (t < 128) {
    float s = 0.f;
#pragma unroll
    for (int r = 0; r < 16; ++r) s += sums_lds[r][t];
    pooled[t] = s / fmaxf((float)(hi - lo), 1.f);
  }
  __syncthreads();
  if (t < 128) {
    float a = b1[t];
    for (int k = 0; k < D; ++k) a += pooled[k] * W1[k * D + t];
    hidden[t] = a;
  }
  __syncthreads();
  if (t < OUT_F) {
    float o = b2[t];
    for (int k = 0; k < D; ++k) o += hidden[k] * W2[k * OUT_F + t];
    out[(size_t)g * OUT_F + t] = o;
  }
}

// ============================== launch ======================================
extern "C" void kernel_launch(void* const* d_in, const int* in_sizes, int n_in,
                              void* d_out, int out_size, void* d_ws, size_t ws_size,
                              hipStream_t stream) {
  const float* x     = (const float*)d_in[0];
  const int*   ei    = (const int*)d_in[1];
  const int*   batch = (const int*)d_in[2];
  const float* Wrel  = (const float*)d_in[3];
  const float* brel  = (const float*)d_in[4];
  const float* Wroot = (const float*)d_in[5];
  const float* W1    = (const float*)d_in[6];
  const float* b1    = (const float*)d_in[7];
  const float* W2    = (const float*)d_in[8];
  const float* b2    = (const float*)d_in[9];
  float* out = (float*)d_out;

  const size_t ND = (size_t)N_NODES * D;
  unsigned short* bufA = (unsigned short*)d_ws;            // N*D bf16
  unsigned short* bufB = bufA + ND;                        // N*D bf16
  unsigned short* bufC = bufB + ND;                        // N*D bf16 (x16)
  unsigned short* wt   = bufC + ND;                        // 3*128*512 bf16
  int* rowbeg = (int*)(wt + (size_t)N_LAYERS * 128 * 512); // N
  int* rowend = rowbeg + N_NODES;                          // N
  int* esrc   = rowend + N_NODES;                          // NBUCK*CAP
  unsigned* pairs = (unsigned*)(esrc + (size_t)NBUCK * CAP);  // NBUCK*CAP
  int* cursor = (int*)(pairs + (size_t)NBUCK * CAP);       // NBUCK

  const int* esrc_in = ei;
  const int* edst_in = ei + N_EDGES;

  // ---- prep (partition + cast + weight frags) then bucket sort ----
  hipMemsetAsync(cursor, 0, NBUCK * sizeof(int), stream);
  prep_part_kernel<<<NB3 + NCAST + NPREPW, 256, 0, stream>>>(
      esrc_in, edst_in, cursor, pairs, x, bufC, Wrel, Wroot, wt);
  bucket_sort_kernel<<<NBUCK, 256, 0, stream>>>(pairs, cursor, rowbeg, rowend, esrc);

  // ---- 3 fused layers (gather + GEMM in one kernel each) ----
  const size_t WL = (size_t)128 * 512;
  layer_kernel<<<NT64, 512, 0, stream>>>(bufC, rowbeg, rowend, esrc,
                                         wt, brel, bufA);
  layer_kernel<<<NT64, 512, 0, stream>>>(bufA, rowbeg, rowend, esrc,
                                         wt + WL, brel + D, bufB);
  layer_kernel<<<NT64, 512, 0, stream>>>(bufB, rowbeg, rowend, esrc,
                                         wt + 2 * WL, brel + 2 * D, bufA);

  pool_head_kernel<<<N_GRAPHS, 256, 0, stream>>>(bufA, batch, W1, b1, W2, b2, out);
}

// Round 16
// 246.828 us; speedup vs baseline: 1.1357x; 1.0363x over previous
//
#include <hip/hip_runtime.h>

#define N_NODES 50000
#define N_EDGES 800000
#define D 128
#define N_LAYERS 3
#define OUT_F 16
#define N_GRAPHS 128
#define NBUCK 391            // ceil(50000/128) buckets of 128 nodes
#define EPB 4096             // edges per partition block
#define NB3 ((N_EDGES + EPB - 1) / EPB)  // 196
#define CAP 4096             // padded bucket capacity (mean 2048, sigma ~45)
#define NT64 ((N_NODES + 63) / 64)       // 782 row-tiles of 64
#define PITCH 132            // LDS tile pitch in shorts (264B)
#define NCAST 6250           // cast blocks: 50000*128/4/256
#define NPREPW 96            // prep_w blocks: 24576/256

typedef __attribute__((ext_vector_type(8))) short short8;
typedef __attribute__((ext_vector_type(16))) float floatx16;

__device__ __forceinline__ unsigned short f2bf(float f) {
  unsigned int u = __float_as_uint(f);
  u += 0x7fff + ((u >> 16) & 1);   // RNE
  return (unsigned short)(u >> 16);
}
__device__ __forceinline__ float bf2f(unsigned short b) {
  return __uint_as_float(((unsigned int)b) << 16);
}
__device__ __forceinline__ float blo(unsigned v) { return __uint_as_float(v << 16); }
__device__ __forceinline__ float bhi(unsigned v) { return __uint_as_float(v & 0xffff0000u); }

// ====== prep_part: partition + cast x + weight frags in ONE dispatch ========
// (cursor zeroed by hipMemsetAsync before this dispatch)
__global__ __launch_bounds__(256) void prep_part_kernel(
    const int* __restrict__ src, const int* __restrict__ dst,
    int* __restrict__ cursor, unsigned* __restrict__ pairs,
    const float* __restrict__ x, unsigned short* __restrict__ x16,
    const float* __restrict__ Wrel, const float* __restrict__ Wroot,
    unsigned short* __restrict__ wt) {
  __shared__ unsigned pk[EPB];
  __shared__ int hist[NBUCK];
  __shared__ int wcur[NBUCK];
  const int bid = blockIdx.x;
  const int t = threadIdx.x;
  if (bid < NB3) {                         // ---- edge partition ----
    const int e0 = bid * EPB;
    const int n = min(EPB, N_EDGES - e0);
    for (int i = t; i < NBUCK; i += 256) hist[i] = 0;
    __syncthreads();
    for (int i = t; i < n; i += 256) {
      int d = dst[e0 + i], s = src[e0 + i];
      pk[i] = ((unsigned)d << 16) | (unsigned)s;
      atomicAdd(&hist[d >> 7], 1);
    }
    __syncthreads();
    for (int i = t; i < NBUCK; i += 256)
      wcur[i] = i * CAP + (hist[i] ? atomicAdd(&cursor[i], hist[i]) : 0);
    __syncthreads();
    for (int i = t; i < n; i += 256) {
      unsigned p = pk[i];
      int pos = atomicAdd(&wcur[p >> 23], 1);
      pairs[pos] = p;
    }
  } else if (bid < NB3 + NCAST) {          // ---- cast x (4 floats/thread) ----
    const int i = (bid - NB3) * 256 + t;
    const float4 v = *(const float4*)&x[(size_t)i * 4];
    uint2 o;
    o.x = f2bf(v.x) | ((unsigned)f2bf(v.y) << 16);
    o.y = f2bf(v.z) | ((unsigned)f2bf(v.w) << 16);
    *(uint2*)&x16[(size_t)i * 4] = o;
  } else {                                 // ---- weight fragments ----
    const int idx = (bid - NB3 - NCAST) * 256 + t;
    const int lane = idx & 63;
    const int kst = (idx >> 6) & 31;
    const int nt = (idx >> 11) & 1;
    const int half = (idx >> 12) & 1;
    const int l = idx >> 13;
    const int n = half * 64 + nt * 32 + (lane & 31);
    const int kx0 = kst * 16 + (lane >> 5) * 8;
    const int seg = kx0 >> 7;              // same seg for all 8 j
    const int k0 = kx0 & 127;
    const int mat = seg >> 1, lo = seg & 1;
    const float* W = (mat ? Wroot : Wrel) + (size_t)l * D * D;
    unsigned short v[8];
#pragma unroll
    for (int j = 0; j < 8; ++j) {
      float w = W[(size_t)(k0 + j) * D + n];
      unsigned short hi = f2bf(w);
      v[j] = lo ? f2bf(w - bf2f(hi)) : hi;
    }
    unsigned short* dstp =
        wt + ((size_t)l * 128 + (half * 2 + nt) * 32 + kst) * 512 + lane * 8;
    *(uint4*)dstp = *(const uint4*)v;
  }
}

__global__ __launch_bounds__(256) void bucket_sort_kernel(
    const unsigned* __restrict__ pairs, const int* __restrict__ cursor,
    int* __restrict__ rowbeg, int* __restrict__ rowend, int* __restrict__ esrc) {
  __shared__ unsigned pk[CAP];
  __shared__ int sorted[CAP];
  __shared__ int hist[128], off[128], cur[128];
  const int bkt = blockIdx.x;
  const int t = threadIdx.x;
  const int beg = bkt * CAP;
  const int cnt = cursor[bkt];
  if (t < 128) hist[t] = 0;
  __syncthreads();
  for (int i = t; i < cnt; i += 256) {
    unsigned p = pairs[beg + i];
    pk[i] = p;
    atomicAdd(&hist[(p >> 16) & 127], 1);
  }
  __syncthreads();
  if (t < 128) off[t] = hist[t];
  __syncthreads();
  for (int o = 1; o < 128; o <<= 1) {
    int x = (t < 128 && t >= o) ? off[t - o] : 0;
    __syncthreads();
    if (t < 128) off[t] += x;
    __syncthreads();
  }
  if (t < 128) {
    int node = bkt * 128 + t;
    if (node < N_NODES) {
      rowbeg[node] = beg + off[t] - hist[t];
      rowend[node] = beg + off[t];
    }
    cur[t] = off[t] - hist[t];
  }
  __syncthreads();
  for (int i = t; i < cnt; i += 256) {
    unsigned p = pk[i];
    int pos = atomicAdd(&cur[(p >> 16) & 127], 1);
    sorted[pos] = (int)(p & 0xFFFFu);
  }
  __syncthreads();
  for (int i = t; i < cnt; i += 256) esrc[beg + i] = sorted[i];
}

// ========== FUSED layer v13: 64-row block, ONE barrier, no redB =============
// 8-wave block = 2 tiles of 32 rows. Gather: 32 groups x 16 lanes, TWO rows
// per group (g and g+32), r4's proven inner loop, (512,8)/32-VGPR config
// (measured best). MFMA: wave w -> (tile w&1, phase w>>1); each wave runs
// BOTH chains (32 ksteps: rel 0-15 from atile, root 16-31 from htile) into
// one accumulator -> no redB exchange, no second barrier.
__global__ __launch_bounds__(512, 8) void layer_kernel(
    const unsigned short* __restrict__ h,     // [N][128] bf16 row-major
    const int* __restrict__ rowbeg, const int* __restrict__ rowend,
    const int* __restrict__ esrc,
    const unsigned short* __restrict__ wt,    // this layer's 128KB frag block
    const float* __restrict__ brel,
    unsigned short* __restrict__ outp) {      // [N][128] bf16 row-major
  __shared__ unsigned short atile[64 * PITCH];  // agg tiles  (16.9 KB)
  __shared__ unsigned short htile[64 * PITCH];  // root tiles (16.9 KB)
  const int t = threadIdx.x;
  const int r0 = blockIdx.x * 64;
  const int g = t >> 4, li = t & 15;            // 32 groups x 16 lanes
  const unsigned short* hp = h + (size_t)li * 8;

#pragma unroll
  for (int rr = 0; rr < 2; ++rr) {
    const int lr = g + rr * 32;
    const int row = r0 + lr;
    // ---- stage root row (coalesced; zero tail rows) ----
    if (row < N_NODES) {
      *(uint4*)&htile[lr * PITCH + li * 8] =
          *(const uint4*)&h[(size_t)row * D + li * 8];
    } else {
      const uint4 z = {0, 0, 0, 0};
      *(uint4*)&htile[lr * PITCH + li * 8] = z;
    }
    // ---- gather: 16 lanes read full 256B source row, 4-edge unroll ----
    int beg = 0, end = 0;
    if (row < N_NODES) { beg = rowbeg[row]; end = rowend[row]; }
    float a0 = 0, a1 = 0, a2 = 0, a3 = 0, a4 = 0, a5 = 0, a6 = 0, a7 = 0;
    int e = beg;
    for (; e + 4 <= end; e += 4) {
      const int s0 = esrc[e],     s1 = esrc[e + 1];
      const int s2 = esrc[e + 2], s3 = esrc[e + 3];
      const uint4 v0 = *(const uint4*)&hp[(size_t)s0 * D];
      const uint4 v1 = *(const uint4*)&hp[(size_t)s1 * D];
      const uint4 v2 = *(const uint4*)&hp[(size_t)s2 * D];
      const uint4 v3 = *(const uint4*)&hp[(size_t)s3 * D];
      a0 += blo(v0.x) + blo(v1.x) + blo(v2.x) + blo(v3.x);
      a1 += bhi(v0.x) + bhi(v1.x) + bhi(v2.x) + bhi(v3.x);
      a2 += blo(v0.y) + blo(v1.y) + blo(v2.y) + blo(v3.y);
      a3 += bhi(v0.y) + bhi(v1.y) + bhi(v2.y) + bhi(v3.y);
      a4 += blo(v0.z) + blo(v1.z) + blo(v2.z) + blo(v3.z);
      a5 += bhi(v0.z) + bhi(v1.z) + bhi(v2.z) + bhi(v3.z);
      a6 += blo(v0.w) + blo(v1.w) + blo(v2.w) + blo(v3.w);
      a7 += bhi(v0.w) + bhi(v1.w) + bhi(v2.w) + bhi(v3.w);
    }
    for (; e < end; ++e) {
      const uint4 v0 = *(const uint4*)&hp[(size_t)esrc[e] * D];
      a0 += blo(v0.x); a1 += bhi(v0.x);
      a2 += blo(v0.y); a3 += bhi(v0.y);
      a4 += blo(v0.z); a5 += bhi(v0.z);
      a6 += blo(v0.w); a7 += bhi(v0.w);
    }
    uint4 o;
    o.x = f2bf(a0) | ((unsigned)f2bf(a1) << 16);
    o.y = f2bf(a2) | ((unsigned)f2bf(a3) << 16);
    o.z = f2bf(a4) | ((unsigned)f2bf(a5) << 16);
    o.w = f2bf(a6) | ((unsigned)f2bf(a7) << 16);
    *(uint4*)&atile[lr * PITCH + li * 8] = o;
  }
  __syncthreads();   // the only barrier

  // ---- MFMA: wave w = (tile w&1, phase w>>1); 32 ksteps, both chains ----
  const int wave = t >> 6, lane = t & 63;
  const int tl = wave & 1, p = wave >> 1;
  const int r2 = lane & 31, hseg = lane >> 5;
  const int rbase = tl * 32 + r2;
  short8 ag[8], hh[8];
#pragma unroll
  for (int i = 0; i < 8; ++i) {
    ag[i] = *(const short8*)&atile[rbase * PITCH + i * 16 + hseg * 8];
    hh[i] = *(const short8*)&htile[rbase * PITCH + i * 16 + hseg * 8];
  }
  const unsigned short* ws = wt + (size_t)p * 32 * 512;
  floatx16 acc = {0.f};
#pragma unroll
  for (int kst = 0; kst < 32; ++kst) {
    const short8 af = (kst < 16) ? ag[kst & 7] : hh[kst & 7];
    const short8 b = *(const short8*)&ws[(size_t)kst * 512 + lane * 8];
    acc = __builtin_amdgcn_mfma_f32_32x32x16_bf16(af, b, acc, 0, 0, 0);
  }
  const int cb = p * 32 + r2;
  const float bias = brel[cb];
#pragma unroll
  for (int reg = 0; reg < 16; ++reg) {
    const int orow = r0 + tl * 32 + (reg & 3) + 8 * (reg >> 2) + 4 * hseg;
    if (orow < N_NODES)
      outp[(size_t)orow * D + cb] = f2bf(fmaxf(acc[reg] + bias, 0.f));
  }
}

// ============= pool (segment ranges; batch sorted) + MLP head ===============
__device__ __forceinline__ int lb_search(const int* __restrict__ a, int n, int key) {
  int lo = 0, hi = n;
  while (lo < hi) {
    int m = (lo + hi) >> 1;
    if (a[m] < key) lo = m + 1; else hi = m;
  }
  return lo;
}

__global__ __launch_bounds__(256) void pool_head_kernel(
    const unsigned short* __restrict__ h, const int* __restrict__ batch,
    const float* __restrict__ W1, const float* __restrict__ b1,
    const float* __restrict__ W2, const float* __restrict__ b2,
    float* __restrict__ out) {
  __shared__ float sums_lds[16][128];
  __shared__ float pooled[128];
  __shared__ float hidden[128];
  __shared__ int range[2];
  const int g = blockIdx.x;
  const int t = threadIdx.x;
  if (t < 2) range[t] = lb_search(batch, N_NODES, g + t);
  __syncthreads();
  const int lo = range[0], hi = range[1];
  const int rg = t >> 4, cg = t & 15;
  float a0 = 0, a1 = 0, a2 = 0, a3 = 0, a4 = 0, a5 = 0, a6 = 0, a7 = 0;
  for (int n = lo + rg; n < hi; n += 16) {
    const uint4 v = *(const uint4*)&h[(size_t)n * D + cg * 8];
    a0 += blo(v.x); a1 += bhi(v.x);
    a2 += blo(v.y); a3 += bhi(v.y);
    a4 += blo(v.z); a5 += bhi(v.z);
    a6 += blo(v.w); a7 += bhi(v.w);
  }
  sums_lds[rg][cg * 8 + 0] = a0; sums_lds[rg][cg * 8 + 1] = a1;
  sums_lds[rg][cg * 8 + 2] = a2; sums_lds[rg][cg * 8 + 3] = a3;
  sums_lds[rg][cg * 8 + 4] = a4; sums_lds[rg][cg * 8 + 5] = a5;
  sums_lds[rg][cg * 8 + 6] = a6; sums_lds[rg][cg * 8 + 7] = a7;
  __syncthreads();
  if (t < 128) {
    float s = 0.f;
#pragma unroll
    for (int r = 0; r < 16; ++r) s += sums_lds[r][t];
    pooled[t] = s / fmaxf((float)(hi - lo), 1.f);
  }
  __syncthreads();
  if (t < 128) {
    float a = b1[t];
    for (int k = 0; k < D; ++k) a += pooled[k] * W1[k * D + t];
    hidden[t] = a;
  }
  __syncthreads();
  if (t < OUT_F) {
    float o = b2[t];
    for (int k = 0; k < D; ++k) o += hidden[k] * W2[k * OUT_F + t];
    out[(size_t)g * OUT_F + t] = o;
  }
}

// ============================== launch ======================================
extern "C" void kernel_launch(void* const* d_in, const int* in_sizes, int n_in,
                              void* d_out, int out_size, void* d_ws, size_t ws_size,
                              hipStream_t stream) {
  const float* x     = (const float*)d_in[0];
  const int*   ei    = (const int*)d_in[1];
  const int*   batch = (const int*)d_in[2];
  const float* Wrel  = (const float*)d_in[3];
  const float* brel  = (const float*)d_in[4];
  const float* Wroot = (const float*)d_in[5];
  const float* W1    = (const float*)d_in[6];
  const float* b1    = (const float*)d_in[7];
  const float* W2    = (const float*)d_in[8];
  const float* b2    = (const float*)d_in[9];
  float* out = (float*)d_out;

  const size_t ND = (size_t)N_NODES * D;
  unsigned short* bufA = (unsigned short*)d_ws;            // N*D bf16
  unsigned short* bufB = bufA + ND;                        // N*D bf16
  unsigned short* bufC = bufB + ND;                        // N*D bf16 (x16)
  unsigned short* wt   = bufC + ND;                        // 3*128*512 bf16
  int* rowbeg = (int*)(wt + (size_t)N_LAYERS * 128 * 512); // N
  int* rowend = rowbeg + N_NODES;                          // N
  int* esrc   = rowend + N_NODES;                          // NBUCK*CAP
  unsigned* pairs = (unsigned*)(esrc + (size_t)NBUCK * CAP);  // NBUCK*CAP
  int* cursor = (int*)(pairs + (size_t)NBUCK * CAP);       // NBUCK

  const int* esrc_in = ei;
  const int* edst_in = ei + N_EDGES;

  // ---- prep (partition + cast + weight frags) then bucket sort ----
  hipMemsetAsync(cursor, 0, NBUCK * sizeof(int), stream);
  prep_part_kernel<<<NB3 + NCAST + NPREPW, 256, 0, stream>>>(
      esrc_in, edst_in, cursor, pairs, x, bufC, Wrel, Wroot, wt);
  bucket_sort_kernel<<<NBUCK, 256, 0, stream>>>(pairs, cursor, rowbeg, rowend, esrc);

  // ---- 3 fused layers (gather + GEMM in one kernel each) ----
  const size_t WL = (size_t)128 * 512;
  layer_kernel<<<NT64, 512, 0, stream>>>(bufC, rowbeg, rowend, esrc,
                                         wt, brel, bufA);
  layer_kernel<<<NT64, 512, 0, stream>>>(bufA, rowbeg, rowend, esrc,
                                         wt + WL, brel + D, bufB);
  layer_kernel<<<NT64, 512, 0, stream>>>(bufB, rowbeg, rowend, esrc,
                                         wt + 2 * WL, brel + 2 * D, bufA);

  pool_head_kernel<<<N_GRAPHS, 256, 0, stream>>>(bufA, batch, W1, b1, W2, b2, out);
}